// Round 6
// baseline (173.068 us; speedup 1.0000x reference)
//
#include <hip/hip_runtime.h>
#include <hip/hip_bf16.h>

#define CIN  32
#define COUT 64
#define KCEN 13
#define FEPS 1e-5f
#define SEGCAP 16384        // >> 9600 expected pairs/k (sigma ~97)

// ws layout (floats):
// [0,32) sums  [32,64) sumsq  [64,96) scale  [96,128) bias
// [128,154) totals[26] (int)  -- pairs per offset
// [160, 160+N*32) xh f32 [N][32]
// A = 160+N*32: cnt/off int[26*nch]   (scan done in place)
// B = A+163840: seg int2[26][SEGCAP]  (src,dst)

#define FMA4(X, WV, a, b, c, d)                         \
    a = fmaf(X.x, WV[0], a); b = fmaf(X.y, WV[1], b);   \
    c = fmaf(X.z, WV[2], c); d = fmaf(X.w, WV[3], d);

__device__ __forceinline__ void dot2(const float4* __restrict__ ra,
                                     const float4* __restrict__ rb,
                                     const float* __restrict__ w,
                                     float& ta, float& tb) {
    float4 a0 = ra[0], a1 = ra[1], a2 = ra[2], a3 = ra[3];
    float4 a4 = ra[4], a5 = ra[5], a6 = ra[6], a7 = ra[7];
    float4 b0 = rb[0], b1 = rb[1], b2 = rb[2], b3 = rb[3];
    float4 b4 = rb[4], b5 = rb[5], b6 = rb[6], b7 = rb[7];
    float p0 = 0.f, p1 = 0.f, p2 = 0.f, p3 = 0.f;
    float q0 = 0.f, q1 = 0.f, q2 = 0.f, q3 = 0.f;
    FMA4(a0, (w + 0), p0, p1, p2, p3)  FMA4(b0, (w + 0), q0, q1, q2, q3)
    FMA4(a1, (w + 4), p0, p1, p2, p3)  FMA4(b1, (w + 4), q0, q1, q2, q3)
    FMA4(a2, (w + 8), p0, p1, p2, p3)  FMA4(b2, (w + 8), q0, q1, q2, q3)
    FMA4(a3, (w + 12), p0, p1, p2, p3) FMA4(b3, (w + 12), q0, q1, q2, q3)
    FMA4(a4, (w + 16), p0, p1, p2, p3) FMA4(b4, (w + 16), q0, q1, q2, q3)
    FMA4(a5, (w + 20), p0, p1, p2, p3) FMA4(b5, (w + 20), q0, q1, q2, q3)
    FMA4(a6, (w + 24), p0, p1, p2, p3) FMA4(b6, (w + 24), q0, q1, q2, q3)
    FMA4(a7, (w + 28), p0, p1, p2, p3) FMA4(b7, (w + 28), q0, q1, q2, q3)
    ta = (p0 + p1) + (p2 + p3);
    tb = (q0 + q1) + (q2 + q3);
}

__device__ __forceinline__ float dot1(const float4* __restrict__ ra,
                                      const float* __restrict__ w) {
    float4 a0 = ra[0], a1 = ra[1], a2 = ra[2], a3 = ra[3];
    float4 a4 = ra[4], a5 = ra[5], a6 = ra[6], a7 = ra[7];
    float p0 = 0.f, p1 = 0.f, p2 = 0.f, p3 = 0.f;
    FMA4(a0, (w + 0), p0, p1, p2, p3)  FMA4(a1, (w + 4), p0, p1, p2, p3)
    FMA4(a2, (w + 8), p0, p1, p2, p3)  FMA4(a3, (w + 12), p0, p1, p2, p3)
    FMA4(a4, (w + 16), p0, p1, p2, p3) FMA4(a5, (w + 20), p0, p1, p2, p3)
    FMA4(a6, (w + 24), p0, p1, p2, p3) FMA4(a7, (w + 28), p0, p1, p2, p3)
    return (p0 + p1) + (p2 + p3);
}

__global__ void k_zero(float* __restrict__ ws) {
    if (threadIdx.x < 160) ws[threadIdx.x] = 0.f;
}

__global__ __launch_bounds__(256) void k_reduce(const float* __restrict__ f,
                                                float* __restrict__ ws, int n4) {
    const float4* f4 = (const float4*)f;
    int tid    = blockIdx.x * blockDim.x + threadIdx.x;
    int stride = gridDim.x * blockDim.x;          // multiple of 8
    float4 s = make_float4(0.f, 0.f, 0.f, 0.f);
    float4 q = make_float4(0.f, 0.f, 0.f, 0.f);
    for (int i = tid; i < n4; i += stride) {
        float4 v = f4[i];
        s.x += v.x; s.y += v.y; s.z += v.z; s.w += v.w;
        q.x = fmaf(v.x, v.x, q.x); q.y = fmaf(v.y, v.y, q.y);
        q.z = fmaf(v.z, v.z, q.z); q.w = fmaf(v.w, v.w, q.w);
    }
    __shared__ float ls[64];
    if (threadIdx.x < 64) ls[threadIdx.x] = 0.f;
    __syncthreads();
    int g = threadIdx.x & 7;
    atomicAdd(&ls[g * 4 + 0], s.x); atomicAdd(&ls[g * 4 + 1], s.y);
    atomicAdd(&ls[g * 4 + 2], s.z); atomicAdd(&ls[g * 4 + 3], s.w);
    atomicAdd(&ls[32 + g * 4 + 0], q.x); atomicAdd(&ls[32 + g * 4 + 1], q.y);
    atomicAdd(&ls[32 + g * 4 + 2], q.z); atomicAdd(&ls[32 + g * 4 + 3], q.w);
    __syncthreads();
    if (threadIdx.x < 64) atomicAdd(&ws[threadIdx.x], ls[threadIdx.x]);
}

__global__ void k_final(const float* __restrict__ gamma, const float* __restrict__ beta,
                        float* __restrict__ ws, float invN) {
    int c = threadIdx.x;                          // 32 threads
    float mean = ws[c] * invN;
    float var  = fmaf(-mean, mean, ws[32 + c] * invN);
    float sc   = gamma[c] * rsqrtf(var + FEPS);
    ws[64 + c] = sc;
    ws[96 + c] = fmaf(-mean, sc, beta[c]);
}

__global__ __launch_bounds__(256) void k_norm(const float* __restrict__ f,
                                              const float* __restrict__ ws,
                                              float* __restrict__ xh, int n4) {
    const float4* f4 = (const float4*)f;
    float4* o4 = (float4*)xh;
    int tid    = blockIdx.x * blockDim.x + threadIdx.x;
    int stride = gridDim.x * blockDim.x;          // multiple of 8
    int g = threadIdx.x & 7;
    float4 sc = ((const float4*)(ws + 64))[g];
    float4 bi = ((const float4*)(ws + 96))[g];
    for (int i = tid; i < n4; i += stride) {
        float4 v = f4[i];
        v.x = fmaxf(fmaf(v.x, sc.x, bi.x), 0.f);
        v.y = fmaxf(fmaf(v.y, sc.y, bi.y), 0.f);
        v.z = fmaxf(fmaf(v.z, sc.z, bi.z), 0.f);
        v.w = fmaxf(fmaf(v.w, sc.w, bi.w), 0.f);
        o4[i] = v;
    }
}

// Per-chunk valid counts. No returning atomics anywhere.
__global__ __launch_bounds__(256) void k_count(const int* __restrict__ nbr,
                                               int* __restrict__ cnt, int n, int nch) {
    int lane = threadIdx.x;
    int k = blockIdx.y; if (k >= KCEN) ++k;
    const int* nk = nbr + (size_t)k * n;
    int wid   = blockIdx.x * 4 + threadIdx.y;
    int waves = gridDim.x * 4;
    int ch = wid;
    if (ch >= nch) return;
    int idx = nk[ch * 64 + lane];
    while (ch < nch) {
        int chn = ch + waves;
        int idxn = (chn < nch) ? nk[chn * 64 + lane] : -1;
        unsigned long long m = __ballot(idx >= 0);
        if (lane == 0) cnt[(size_t)blockIdx.y * nch + ch] = __popcll(m);
        idx = idxn; ch = chn;
    }
}

// In-place exclusive scan of each offset's nch counts; one block per offset.
__global__ __launch_bounds__(1024) void k_scan(int* __restrict__ cnt,
                                               int* __restrict__ tot, int nch) {
    const int EPT = 7;                            // 1024*7 >= 6250
    int* c = cnt + (size_t)blockIdx.x * nch;
    int t = threadIdx.x, lane = t & 63, wv = t >> 6;
    int base = t * EPT;
    int v[EPT];
    int sum = 0;
#pragma unroll
    for (int i = 0; i < EPT; ++i) {
        int e = base + i;
        v[i] = (e < nch) ? c[e] : 0;
        sum += v[i];
    }
    int incl = sum;
#pragma unroll
    for (int d = 1; d < 64; d <<= 1) {
        int x = __shfl_up(incl, d);
        if (lane >= d) incl += x;
    }
    __shared__ int wsum[16];
    __shared__ int woff[16];
    if (lane == 63) wsum[wv] = incl;
    __syncthreads();
    if (t == 0) {
        int a = 0;
        for (int i = 0; i < 16; ++i) { woff[i] = a; a += wsum[i]; }
        tot[blockIdx.x] = a;
    }
    __syncthreads();
    int excl = woff[wv] + (incl - sum);
#pragma unroll
    for (int i = 0; i < EPT; ++i) {
        int e = base + i;
        if (e < nch) { int val = v[i]; c[e] = excl; excl += val; }
    }
}

// Write dense (src,dst) pair lists at scanned offsets.
__global__ __launch_bounds__(256) void k_fill(const int* __restrict__ nbr,
                                              const int* __restrict__ off,
                                              int2* __restrict__ seg, int n, int nch) {
    int lane = threadIdx.x;
    int k = blockIdx.y; if (k >= KCEN) ++k;
    const int* nk = nbr + (size_t)k * n;
    int2* sg = seg + (size_t)blockIdx.y * SEGCAP;
    int wid   = blockIdx.x * 4 + threadIdx.y;
    int waves = gridDim.x * 4;
    int ch = wid;
    if (ch >= nch) return;
    int idx = nk[ch * 64 + lane];
    while (ch < nch) {
        int chn = ch + waves;
        int idxn = (chn < nch) ? nk[chn * 64 + lane] : -1;
        unsigned long long m = __ballot(idx >= 0);
        if (idx >= 0) {
            int pos = off[(size_t)blockIdx.y * nch + ch]
                    + __popcll(m & ((1ull << lane) - 1ull));
            if (pos < SEGCAP) sg[pos] = make_int2(idx, ch * 64 + lane);
        }
        idx = idxn; ch = chn;
    }
}

// Dense center pass: one 64-row tile per block, LDS-staged, plain stores
// double as the zero-init of out.
__global__ __launch_bounds__(256, 4) void k_center(const float* __restrict__ xh,
                                                   const float* __restrict__ W,
                                                   float* __restrict__ out, int n) {
    __shared__ float xs[64 * CIN];                 // 8 KB
    int lane = threadIdx.x & 63;
    int wv   = threadIdx.x >> 6;

    float w[CIN];
#pragma unroll
    for (int c = 0; c < CIN; ++c) w[c] = W[(size_t)KCEN * (CIN * COUT) + c * COUT + lane];

    int r0 = blockIdx.x * 64;                      // grid = n/64
    const float4* src = (const float4*)(xh + (size_t)r0 * CIN);
    float4* dst = (float4*)xs;
    dst[threadIdx.x]       = src[threadIdx.x];
    dst[threadIdx.x + 256] = src[threadIdx.x + 256];
    __syncthreads();

#pragma unroll
    for (int rr = 0; rr < 16; rr += 2) {
        int r = wv * 16 + rr;
        const float4* ra = (const float4*)&xs[(r + 0) * CIN];
        const float4* rb = (const float4*)&xs[(r + 1) * CIN];
        float t0, t1;
        dot2(ra, rb, w, t0, t1);
        out[(size_t)(r0 + r + 0) * COUT + lane] = t0;
        out[(size_t)(r0 + r + 1) * COUT + lane] = t1;
    }
}

// Dense pair GEMV: quads of pairs, 16 row-loads in flight, W amortized ~60x.
__global__ __launch_bounds__(256, 4) void k_pairs(const float* __restrict__ xh,
                                                  const float* __restrict__ W,
                                                  const int* __restrict__ tot,
                                                  const int2* __restrict__ seg,
                                                  float* __restrict__ out) {
    int lane = threadIdx.x;
    int k = blockIdx.y; if (k >= KCEN) ++k;
    float w[CIN];
#pragma unroll
    for (int c = 0; c < CIN; ++c) w[c] = W[(size_t)k * (CIN * COUT) + c * COUT + lane];

    int nc = tot[blockIdx.y]; if (nc > SEGCAP) nc = SEGCAP;
    const int2* sg = seg + (size_t)blockIdx.y * SEGCAP;
    int wid   = blockIdx.x * 4 + threadIdx.y;
    int waves = gridDim.x * 4;

    for (int j = wid * 4; j <= nc - 4; j += waves * 4) {
        int2 p0 = sg[j], p1 = sg[j + 1], p2 = sg[j + 2], p3 = sg[j + 3];
        int s0 = __builtin_amdgcn_readfirstlane(p0.x), d0 = __builtin_amdgcn_readfirstlane(p0.y);
        int s1 = __builtin_amdgcn_readfirstlane(p1.x), d1 = __builtin_amdgcn_readfirstlane(p1.y);
        int s2 = __builtin_amdgcn_readfirstlane(p2.x), d2 = __builtin_amdgcn_readfirstlane(p2.y);
        int s3 = __builtin_amdgcn_readfirstlane(p3.x), d3 = __builtin_amdgcn_readfirstlane(p3.y);
        float t0, t1, t2, t3;
        dot2((const float4*)(xh + (size_t)s0 * CIN),
             (const float4*)(xh + (size_t)s1 * CIN), w, t0, t1);
        dot2((const float4*)(xh + (size_t)s2 * CIN),
             (const float4*)(xh + (size_t)s3 * CIN), w, t2, t3);
        unsafeAtomicAdd(&out[(size_t)d0 * COUT + lane], t0);
        unsafeAtomicAdd(&out[(size_t)d1 * COUT + lane], t1);
        unsafeAtomicAdd(&out[(size_t)d2 * COUT + lane], t2);
        unsafeAtomicAdd(&out[(size_t)d3 * COUT + lane], t3);
    }
    // final partial quad (nc % 4 pairs), done by its owning wave
    int q4 = nc & ~3;
    if (q4 < nc && wid == ((q4 >> 2) % waves)) {
        for (int j = q4; j < nc; ++j) {
            int2 p = sg[j];
            int s = __builtin_amdgcn_readfirstlane(p.x);
            int d = __builtin_amdgcn_readfirstlane(p.y);
            float t = dot1((const float4*)(xh + (size_t)s * CIN), w);
            unsafeAtomicAdd(&out[(size_t)d * COUT + lane], t);
        }
    }
}

extern "C" void kernel_launch(void* const* d_in, const int* in_sizes, int n_in,
                              void* d_out, int out_size, void* d_ws, size_t ws_size,
                              hipStream_t stream) {
    const float* feat  = (const float*)d_in[0];
    const float* gamma = (const float*)d_in[1];
    const float* beta  = (const float*)d_in[2];
    const float* W     = (const float*)d_in[3];
    const int*   nbr   = (const int*)d_in[4];
    float* out = (float*)d_out;
    float* ws  = (float*)d_ws;

    int n   = in_sizes[0] / CIN;                  // 400000
    int n4  = in_sizes[0] / 4;
    int nch = n >> 6;                             // 6250 chunks (n % 64 == 0)
    float* xh  = ws + 160;
    int*   tot = (int*)(ws + 128);                // totals[26]
    int*   cnt = (int*)(ws + 160 + (size_t)n * 32);
    int2*  seg = (int2*)((char*)cnt + 163840 * 4);

    hipLaunchKernelGGL(k_zero,   dim3(1), dim3(256), 0, stream, ws);
    hipLaunchKernelGGL(k_count,  dim3(64, 26), dim3(64, 4), 0, stream, nbr, cnt, n, nch);
    hipLaunchKernelGGL(k_scan,   dim3(26), dim3(1024), 0, stream, cnt, tot, nch);
    hipLaunchKernelGGL(k_reduce, dim3(512), dim3(256), 0, stream, feat, ws, n4);
    hipLaunchKernelGGL(k_final,  dim3(1), dim3(32), 0, stream, gamma, beta, ws, 1.0f / (float)n);
    hipLaunchKernelGGL(k_norm,   dim3(2048), dim3(256), 0, stream, feat, ws, xh, n4);
    hipLaunchKernelGGL(k_fill,   dim3(64, 26), dim3(64, 4), 0, stream, nbr, cnt, seg, n, nch);
    hipLaunchKernelGGL(k_center, dim3(nch), dim3(256), 0, stream, xh, W, out, n);
    hipLaunchKernelGGL(k_pairs,  dim3(40, 26), dim3(64, 4), 0, stream, xh, W, tot, seg, out);
}

// Round 7
// 117.810 us; speedup vs baseline: 1.4690x; 1.4690x over previous
//
#include <hip/hip_runtime.h>
#include <hip/hip_bf16.h>

#define CIN  32
#define COUT 64
#define KVOL 27
#define FEPS 1e-5f

typedef __attribute__((ext_vector_type(8))) short short8;
typedef __attribute__((ext_vector_type(4))) float f32x4;

// ws float layout:
// [0,32) sums   [32,64) sumsq   [64,96) scale   [96,128) bias
// [128, 128+27648)  Bf: bf16 B-fragments, uint4[27][4][64]
// [27776, 27776+N*16)  xh bf16-packed [N][32ch] (64B per row)

__device__ __forceinline__ unsigned bfr(float f) {   // f32 -> bf16 bits, RNE
    unsigned u = __float_as_uint(f);
    return (u + 0x7FFFu + ((u >> 16) & 1u)) >> 16;
}

__global__ void k_zero(float* __restrict__ ws) {
    if (threadIdx.x < 64) ws[threadIdx.x] = 0.f;
}

__global__ __launch_bounds__(256) void k_reduce(const float* __restrict__ f,
                                                float* __restrict__ ws, int n4) {
    const float4* f4 = (const float4*)f;
    int tid    = blockIdx.x * blockDim.x + threadIdx.x;
    int stride = gridDim.x * blockDim.x;          // multiple of 8
    float4 s = make_float4(0.f, 0.f, 0.f, 0.f);
    float4 q = make_float4(0.f, 0.f, 0.f, 0.f);
    for (int i = tid; i < n4; i += stride) {
        float4 v = f4[i];
        s.x += v.x; s.y += v.y; s.z += v.z; s.w += v.w;
        q.x = fmaf(v.x, v.x, q.x); q.y = fmaf(v.y, v.y, q.y);
        q.z = fmaf(v.z, v.z, q.z); q.w = fmaf(v.w, v.w, q.w);
    }
    __shared__ float ls[64];
    if (threadIdx.x < 64) ls[threadIdx.x] = 0.f;
    __syncthreads();
    int g = threadIdx.x & 7;
    atomicAdd(&ls[g * 4 + 0], s.x); atomicAdd(&ls[g * 4 + 1], s.y);
    atomicAdd(&ls[g * 4 + 2], s.z); atomicAdd(&ls[g * 4 + 3], s.w);
    atomicAdd(&ls[32 + g * 4 + 0], q.x); atomicAdd(&ls[32 + g * 4 + 1], q.y);
    atomicAdd(&ls[32 + g * 4 + 2], q.z); atomicAdd(&ls[32 + g * 4 + 3], q.w);
    __syncthreads();
    if (threadIdx.x < 64) atomicAdd(&ws[threadIdx.x], ls[threadIdx.x]);
}

__global__ void k_final(const float* __restrict__ gamma, const float* __restrict__ beta,
                        float* __restrict__ ws, float invN) {
    int c = threadIdx.x;                          // 32 threads
    float mean = ws[c] * invN;
    float var  = fmaf(-mean, mean, ws[32 + c] * invN);
    float sc   = gamma[c] * rsqrtf(var + FEPS);
    ws[64 + c] = sc;
    ws[96 + c] = fmaf(-mean, sc, beta[c]);
}

// xhat = relu(f*scale+bias) packed to bf16; 8 channels/thread, uint4 stores.
__global__ __launch_bounds__(256) void k_norm(const float* __restrict__ f,
                                              const float* __restrict__ ws,
                                              uint4* __restrict__ xb, int n8) {
    const float4* f4 = (const float4*)f;
    int tid    = blockIdx.x * blockDim.x + threadIdx.x;
    int stride = gridDim.x * blockDim.x;          // multiple of 4
    int g = tid & 3;                              // channel group 8g..8g+7
    float4 s0 = ((const float4*)(ws + 64))[2 * g];
    float4 s1 = ((const float4*)(ws + 64))[2 * g + 1];
    float4 b0 = ((const float4*)(ws + 96))[2 * g];
    float4 b1 = ((const float4*)(ws + 96))[2 * g + 1];
    for (int i = tid; i < n8; i += stride) {
        float4 v0 = f4[2 * i], v1 = f4[2 * i + 1];
        v0.x = fmaxf(fmaf(v0.x, s0.x, b0.x), 0.f);
        v0.y = fmaxf(fmaf(v0.y, s0.y, b0.y), 0.f);
        v0.z = fmaxf(fmaf(v0.z, s0.z, b0.z), 0.f);
        v0.w = fmaxf(fmaf(v0.w, s0.w, b0.w), 0.f);
        v1.x = fmaxf(fmaf(v1.x, s1.x, b1.x), 0.f);
        v1.y = fmaxf(fmaf(v1.y, s1.y, b1.y), 0.f);
        v1.z = fmaxf(fmaf(v1.z, s1.z, b1.z), 0.f);
        v1.w = fmaxf(fmaf(v1.w, s1.w, b1.w), 0.f);
        uint4 r;
        r.x = bfr(v0.x) | (bfr(v0.y) << 16);
        r.y = bfr(v0.z) | (bfr(v0.w) << 16);
        r.z = bfr(v1.x) | (bfr(v1.y) << 16);
        r.w = bfr(v1.z) | (bfr(v1.w) << 16);
        xb[i] = r;
    }
}

// Build bf16 B-fragments for all 27 offsets.
// Fragment convention (consistent with the A-gather in k_conv, so any k-order
// permutation cancels): lane holds B[k=(lane>>4)*8+e][n=nt*16+(lane&15)].
__global__ __launch_bounds__(256) void k_prep(const float* __restrict__ W,
                                              uint4* __restrict__ Bf) {
    int k    = blockIdx.x;
    int nt   = threadIdx.x >> 6;
    int lane = threadIdx.x & 63;
    int col  = nt * 16 + (lane & 15);
    int kk   = (lane >> 4) * 8;
    const float* Wk = W + (size_t)k * (CIN * COUT);
    unsigned r[4];
#pragma unroll
    for (int e = 0; e < 4; ++e) {
        unsigned lo = bfr(Wk[(kk + 2 * e) * COUT + col]);
        unsigned hi = bfr(Wk[(kk + 2 * e + 1) * COUT + col]);
        r[e] = lo | (hi << 16);
    }
    Bf[(size_t)(k * 4 + nt) * 64 + lane] = make_uint4(r[0], r[1], r[2], r[3]);
}

// Output-stationary MFMA conv: one 16-voxel tile per wave, loop over 27
// offsets with ballot-skip, per-lane A-gather (16 rows fetched by ONE
// dwordx4), 4x mfma_f32_16x16x32_bf16 into f32 accumulators, single store.
__global__ __launch_bounds__(256, 4) void k_conv(const char* __restrict__ xhb,
                                                 const uint4* __restrict__ Bf,
                                                 const int* __restrict__ nbr,
                                                 float* __restrict__ out, int n) {
    int lane = threadIdx.x & 63;
    int wv   = threadIdx.x >> 6;
    int r0   = (blockIdx.x * 4 + wv) * 16;         // tile base row
    int rl   = r0 + (lane & 15);                   // this lane's voxel
    int koff = (lane >> 4) * 16;                   // byte offset within 64B row

    f32x4 acc0 = {0.f, 0.f, 0.f, 0.f};
    f32x4 acc1 = acc0, acc2 = acc0, acc3 = acc0;

    int idx = nbr[rl];                             // k = 0
    for (int k = 0; k < KVOL; ++k) {
        int idxn = (k < KVOL - 1) ? nbr[(size_t)(k + 1) * n + rl] : -1;
        unsigned long long m = __ballot(idx >= 0);
        if (m) {
            int src = (idx >= 0) ? idx : 0;
            uint4 a = *(const uint4*)(xhb + ((size_t)src << 6) + koff);
            if (idx < 0) { a.x = 0u; a.y = 0u; a.z = 0u; a.w = 0u; }
            short8 av = __builtin_bit_cast(short8, a);
            const uint4* bk = Bf + (size_t)k * 256 + lane;
            short8 b0 = __builtin_bit_cast(short8, bk[0]);
            short8 b1 = __builtin_bit_cast(short8, bk[64]);
            short8 b2 = __builtin_bit_cast(short8, bk[128]);
            short8 b3 = __builtin_bit_cast(short8, bk[192]);
            acc0 = __builtin_amdgcn_mfma_f32_16x16x32_bf16(av, b0, acc0, 0, 0, 0);
            acc1 = __builtin_amdgcn_mfma_f32_16x16x32_bf16(av, b1, acc1, 0, 0, 0);
            acc2 = __builtin_amdgcn_mfma_f32_16x16x32_bf16(av, b2, acc2, 0, 0, 0);
            acc3 = __builtin_amdgcn_mfma_f32_16x16x32_bf16(av, b3, acc3, 0, 0, 0);
        }
        idx = idxn;
    }

    // C/D layout (verified): col = lane&15, row = (lane>>4)*4 + reg
    float* op = out + (size_t)(r0 + (lane >> 4) * 4) * COUT + (lane & 15);
#pragma unroll
    for (int j = 0; j < 4; ++j) {
        op[j * COUT +  0] = acc0[j];
        op[j * COUT + 16] = acc1[j];
        op[j * COUT + 32] = acc2[j];
        op[j * COUT + 48] = acc3[j];
    }
}

extern "C" void kernel_launch(void* const* d_in, const int* in_sizes, int n_in,
                              void* d_out, int out_size, void* d_ws, size_t ws_size,
                              hipStream_t stream) {
    const float* feat  = (const float*)d_in[0];
    const float* gamma = (const float*)d_in[1];
    const float* beta  = (const float*)d_in[2];
    const float* W     = (const float*)d_in[3];
    const int*   nbr   = (const int*)d_in[4];
    float* out = (float*)d_out;
    float* ws  = (float*)d_ws;

    int n  = in_sizes[0] / CIN;                   // 400000
    int n4 = in_sizes[0] / 4;
    int n8 = in_sizes[0] / 8;
    uint4* Bf  = (uint4*)(ws + 128);
    uint4* xb  = (uint4*)(ws + 27776);            // bf16 xhat, 64B rows
    char*  xhb = (char*)xb;

    hipLaunchKernelGGL(k_zero,   dim3(1), dim3(64), 0, stream, ws);
    hipLaunchKernelGGL(k_prep,   dim3(KVOL), dim3(256), 0, stream, W, Bf);
    hipLaunchKernelGGL(k_reduce, dim3(512), dim3(256), 0, stream, feat, ws, n4);
    hipLaunchKernelGGL(k_final,  dim3(1), dim3(32), 0, stream, gamma, beta, ws, 1.0f / (float)n);
    hipLaunchKernelGGL(k_norm,   dim3(2048), dim3(256), 0, stream, feat, ws, xb, n8);
    hipLaunchKernelGGL(k_conv,   dim3(n / 64), dim3(256), 0, stream, xhb, Bf, nbr, out, n);
}